// Round 5
// baseline (550.026 us; speedup 1.0000x reference)
//
#include <hip/hip_runtime.h>

// PPNet forward, round 5.
// - fused_k per layer: g1 -> g2(gate packed bf16 in regs) -> h -> BN*gate
//   epilogue -> store X_next + next layer's BN stats (GEMM + atomics).
// - amdgpu_waves_per_eu(3,3) on fused_k: pins occupancy so the allocator
//   can't chase a higher-occupancy tier and spill (round 3: 84 regs/r4: 128
//   regs + ~56MB scratch traffic). Budget 170 regs, natural ~140.
// - LDS tiles use +8-element row padding instead of XOR swizzle: additive
//   addressing folds k0 into ds_read immediate offsets; 528B row stride
//   rotates banks 4/row, rows m & m+8 alias 2-way (free).
// - embed+stats0 fused: gathered gin tile reused in-LDS for the 4-domain
//   layer-0 stats GEMM. Dispatches: prep, embed_stats, fused0, fused1, fused2.

typedef __attribute__((ext_vector_type(8))) short short8;
typedef __attribute__((ext_vector_type(4))) float floatx4;

#define BATCH 32768
#define NDOM 4
#define TM 64

__device__ __forceinline__ unsigned short f2b(float f) {
    unsigned u = __float_as_uint(f);
    u += 0x7fffu + ((u >> 16) & 1u);  // round-to-nearest-even
    return (unsigned short)(u >> 16);
}
__device__ __forceinline__ float b2f(unsigned short h) {
    return __uint_as_float(((unsigned)h) << 16);
}

// ---------------------------------------------------------------------------
// Weight prep: fp32 (D,K,N) -> bf16 (D,N,K) packed; zero stat accumulators.
struct MatDesc { const float* src; unsigned K, N, pfx, total; };
struct PrepArgs { MatDesc m[9]; float* stats; unsigned statsN; unsigned grand; };

__global__ __launch_bounds__(256) void prep_k(PrepArgs a, unsigned short* __restrict__ wt) {
    unsigned e = blockIdx.x * 256 + threadIdx.x;
    if (e < a.statsN) a.stats[e] = 0.f;
    if (e >= a.grand) return;
    int j = 0;
    while (j < 8 && e >= a.m[j].pfx + a.m[j].total) j++;
    const unsigned K = a.m[j].K, N = a.m[j].N;
    const unsigned local = e - a.m[j].pfx;
    const unsigned kn = K * N;
    const unsigned d = local / kn;
    const unsigned r2 = local - d * kn;
    const unsigned n = r2 / K;
    const unsigned k = r2 - n * K;
    wt[e] = f2b(a.m[j].src[((long long)d * K + k) * N + n]);
}

// ---------------------------------------------------------------------------
// Embedding gather + layer-0 BN stats, fused. One block = 64 rows.
// Phase 1: gather 16-float embedding slots -> bf16 -> LDS (padded layout).
// Phase 2: coalesced store of gin. Phase 3: per-domain stats GEMM from LDS.
__global__ __launch_bounds__(256) __attribute__((amdgpu_waves_per_eu(4, 4)))
void embed_stats_k(const int* __restrict__ idi, const int* __restrict__ agi,
                   const float* __restrict__ idt, const float* __restrict__ agt,
                   const unsigned short* __restrict__ Wm0,
                   unsigned short* __restrict__ gin,
                   float* __restrict__ gsum, float* __restrict__ gssq) {
    constexpr int LDP = 264;  // 256 + 8 pad
    __shared__ __align__(16) unsigned short buf[TM * LDP];
    const int t = threadIdx.x;
    const int m0 = blockIdx.x * TM;

    {  // gather: thread t -> row r = t>>2, slots (t&3)*4 .. +3
        int r = t >> 2, sp = t & 3;
        int b = m0 + r;
#pragma unroll
        for (int ss = 0; ss < 4; ss++) {
            int s = sp * 4 + ss;
            int f = s & 7;
            const int* ip = (s < 8) ? idi : agi;
            const float* tab = (s < 8) ? idt : agt;
            int ix = ip[b * 8 + f];
            const float* src = tab + ((long long)f * 100000 + ix) * 16;
            unsigned short tmp[16];
#pragma unroll
            for (int j = 0; j < 16; j++) tmp[j] = f2b(src[j]);
            unsigned short* dst = &buf[r * LDP + s * 16];
            *(uint4*)dst = *(const uint4*)tmp;
            *(uint4*)(dst + 8) = *(const uint4*)(tmp + 8);
        }
    }
    __syncthreads();

    {  // coalesced gin store
        unsigned short* Gp = gin + (long long)m0 * 256;
#pragma unroll
        for (int it = 0; it < 8; it++) {
            int idx = it * 256 + t;
            int m = idx >> 5, j = idx & 31;
            *(uint4*)(Gp + (long long)m * 256 + j * 8) = *(const uint4*)&buf[m * LDP + j * 8];
        }
    }

    // stats GEMM: h0_pre = gin @ Wm0[d], per-(d,n) sum/ssq, d sequential
    const int w = t >> 6, lane = t & 63, lrow = lane & 15, lq = lane >> 4;
    const int n0w = w * 64;
    for (int d = 0; d < NDOM; d++) {
        const unsigned short* Wp = Wm0 + ((long long)d * 256 + n0w) * 256;
        floatx4 acc[4][4];
#pragma unroll
        for (int rt = 0; rt < 4; rt++)
#pragma unroll
            for (int ct = 0; ct < 4; ct++) acc[rt][ct] = (floatx4)(0.f);
#pragma unroll
        for (int k0 = 0; k0 < 256; k0 += 32) {
            short8 a[4], bb[4];
#pragma unroll
            for (int rt = 0; rt < 4; rt++)
                a[rt] = *(const short8*)&buf[(rt * 16 + lrow) * LDP + k0 + lq * 8];
#pragma unroll
            for (int ct = 0; ct < 4; ct++)
                bb[ct] = *(const short8*)(Wp + (long long)(ct * 16 + lrow) * 256 + k0 + lq * 8);
#pragma unroll
            for (int rt = 0; rt < 4; rt++)
#pragma unroll
                for (int ct = 0; ct < 4; ct++)
                    acc[rt][ct] = __builtin_amdgcn_mfma_f32_16x16x32_bf16(a[rt], bb[ct], acc[rt][ct], 0, 0, 0);
        }
#pragma unroll
        for (int ct = 0; ct < 4; ct++) {
            float s = 0.f, ss = 0.f;
#pragma unroll
            for (int rt = 0; rt < 4; rt++)
#pragma unroll
                for (int r = 0; r < 4; r++) { float v = acc[rt][ct][r]; s += v; ss += v * v; }
            s += __shfl_down(s, 32); ss += __shfl_down(ss, 32);
            s += __shfl_down(s, 16); ss += __shfl_down(ss, 16);
            if (lane < 16) {
                atomicAdd(&gsum[d * 256 + n0w + ct * 16 + lane], s);
                atomicAdd(&gssq[d * 256 + n0w + ct * 16 + lane], ss);
            }
        }
    }
}

// ---------------------------------------------------------------------------
// Fused layer kernel. N: layer width. KX: h-input width. NN: next layer
// width (0 = last -> final dot+select). GINH: h-input is gin (layer 0).
template <int N, int KX, int NN, bool GINH, bool FINAL>
__global__ __launch_bounds__(256) __attribute__((amdgpu_waves_per_eu(3, 3)))
void fused_k(
    const unsigned short* __restrict__ gin,
    const unsigned short* __restrict__ Xh,
    const unsigned short* __restrict__ W1,   // [d][N][256]
    const unsigned short* __restrict__ W2,   // [d][N][N]
    const unsigned short* __restrict__ Wm,   // [d][N][KX]
    const unsigned short* __restrict__ WmN,  // [d][NN][N]
    const float* __restrict__ gb1, const float* __restrict__ gb2,
    const float* __restrict__ gsum, const float* __restrict__ gssq,
    const float* __restrict__ gma, const float* __restrict__ bta,
    float* __restrict__ gsumN, float* __restrict__ gssqN,
    unsigned short* __restrict__ Xn,
    const int* __restrict__ dom, const float* __restrict__ fw,
    const float* __restrict__ fb, float* __restrict__ outp, float invB) {
    constexpr int LDG = 264;      // gin tile row stride (256+8)
    constexpr int LDN = N + 8;    // g1b / X_next tile row stride
    constexpr int LDX = KX + 8;   // h-input tile row stride
    constexpr int CT = N / 64;    // col tiles per wave
    constexpr int CTn = (NN > 0) ? (NN / 64) : 1;
    __shared__ __align__(16) unsigned short buf[TM * LDG];
    __shared__ float sSC[N], sSH[N];
    __shared__ float sSum[NN > 0 ? NN : 1], sSsq[NN > 0 ? NN : 1];

    const int t = threadIdx.x;
    const int d = blockIdx.y;
    const int m0 = blockIdx.x * TM;
    const int w = t >> 6, lane = t & 63, lrow = lane & 15, lq = lane >> 4;
    const int n0w = w * (N / 4);

    // prologue: BN affine from stats (mlp bias cancels in BN)
    if (t < N) {
        float ma = gsum[d * N + t] * invB;
        float var = gssq[d * N + t] * invB - ma * ma;
        float sc = rsqrtf(var + 1e-5f) * gma[d * N + t];
        sSC[t] = sc;
        sSH[t] = bta[d * N + t] - ma * sc;
    }
    if (NN > 0 && t < NN) { sSum[t] = 0.f; sSsq[t] = 0.f; }

    {  // stage gin tile (64 x 256) into padded layout
        const unsigned short* Gp = gin + (long long)m0 * 256;
#pragma unroll
        for (int it = 0; it < 8; it++) {
            int idx = it * 256 + t;
            int m = idx >> 5, j = idx & 31;
            *(uint4*)&buf[m * LDG + j * 8] = *(const uint4*)(Gp + (long long)m * 256 + j * 8);
        }
    }
    __syncthreads();

    // ---- g1 = relu(gin @ W1 + b1)
    floatx4 acc1[4][CT];
#pragma unroll
    for (int rt = 0; rt < 4; rt++)
#pragma unroll
        for (int ct = 0; ct < CT; ct++) acc1[rt][ct] = (floatx4)(0.f);
    {
        const unsigned short* W1p = W1 + ((long long)d * N + n0w) * 256;
#pragma unroll
        for (int k0 = 0; k0 < 256; k0 += 32) {
            short8 a[4], b[CT];
#pragma unroll
            for (int rt = 0; rt < 4; rt++)
                a[rt] = *(const short8*)&buf[(rt * 16 + lrow) * LDG + k0 + lq * 8];
#pragma unroll
            for (int ct = 0; ct < CT; ct++)
                b[ct] = *(const short8*)(W1p + (long long)(ct * 16 + lrow) * 256 + k0 + lq * 8);
#pragma unroll
            for (int rt = 0; rt < 4; rt++)
#pragma unroll
                for (int ct = 0; ct < CT; ct++)
                    acc1[rt][ct] = __builtin_amdgcn_mfma_f32_16x16x32_bf16(a[rt], b[ct], acc1[rt][ct], 0, 0, 0);
        }
    }
    __syncthreads();  // g1 A-reads done; buf reusable
#pragma unroll
    for (int ct = 0; ct < CT; ct++) {
        int n = n0w + ct * 16 + lrow;
        float bs = gb1[d * N + n];
#pragma unroll
        for (int rt = 0; rt < 4; rt++)
#pragma unroll
            for (int r = 0; r < 4; r++) {
                int m = rt * 16 + lq * 4 + r;
                buf[m * LDN + n] = f2b(fmaxf(acc1[rt][ct][r] + bs, 0.f));
            }
    }
    __syncthreads();

    // ---- gate = 2*sigmoid(g1 @ W2 + b2), packed bf16 pairs in regs
    floatx4 acc2[4][CT];
#pragma unroll
    for (int rt = 0; rt < 4; rt++)
#pragma unroll
        for (int ct = 0; ct < CT; ct++) acc2[rt][ct] = (floatx4)(0.f);
    {
        const unsigned short* W2p = W2 + ((long long)d * N + n0w) * N;
#pragma unroll
        for (int k0 = 0; k0 < N; k0 += 32) {
            short8 a[4], b[CT];
#pragma unroll
            for (int rt = 0; rt < 4; rt++)
                a[rt] = *(const short8*)&buf[(rt * 16 + lrow) * LDN + k0 + lq * 8];
#pragma unroll
            for (int ct = 0; ct < CT; ct++)
                b[ct] = *(const short8*)(W2p + (long long)(ct * 16 + lrow) * N + k0 + lq * 8);
#pragma unroll
            for (int rt = 0; rt < 4; rt++)
#pragma unroll
                for (int ct = 0; ct < CT; ct++)
                    acc2[rt][ct] = __builtin_amdgcn_mfma_f32_16x16x32_bf16(a[rt], b[ct], acc2[rt][ct], 0, 0, 0);
        }
    }
    unsigned gatep[4][CT][2];
#pragma unroll
    for (int ct = 0; ct < CT; ct++) {
        int n = n0w + ct * 16 + lrow;
        float bs = gb2[d * N + n];
#pragma unroll
        for (int rt = 0; rt < 4; rt++) {
            float g0 = 2.f / (1.f + __expf(-(acc2[rt][ct][0] + bs)));
            float g1 = 2.f / (1.f + __expf(-(acc2[rt][ct][1] + bs)));
            float g2 = 2.f / (1.f + __expf(-(acc2[rt][ct][2] + bs)));
            float g3 = 2.f / (1.f + __expf(-(acc2[rt][ct][3] + bs)));
            gatep[rt][ct][0] = (unsigned)f2b(g0) | ((unsigned)f2b(g1) << 16);
            gatep[rt][ct][1] = (unsigned)f2b(g2) | ((unsigned)f2b(g3) << 16);
        }
    }
    __syncthreads();  // g2 A-reads done

    {  // restage h-input tile (padded stride LDX)
        const unsigned short* Xp = GINH ? (gin + (long long)m0 * KX)
                                        : (Xh + ((long long)d * BATCH + m0) * KX);
#pragma unroll
        for (int it = 0; it < KX / 32; it++) {
            int idx = it * 256 + t;
            int m = idx / (KX / 8), j = idx % (KX / 8);
            *(uint4*)&buf[m * LDX + j * 8] = *(const uint4*)(Xp + (long long)m * KX + j * 8);
        }
    }
    __syncthreads();

    // ---- h = X @ Wm (bias folded into SH)
    floatx4 acch[4][CT];
#pragma unroll
    for (int rt = 0; rt < 4; rt++)
#pragma unroll
        for (int ct = 0; ct < CT; ct++) acch[rt][ct] = (floatx4)(0.f);
    {
        const unsigned short* Wmp = Wm + ((long long)d * N + n0w) * KX;
#pragma unroll
        for (int k0 = 0; k0 < KX; k0 += 32) {
            short8 a[4], b[CT];
#pragma unroll
            for (int rt = 0; rt < 4; rt++)
                a[rt] = *(const short8*)&buf[(rt * 16 + lrow) * LDX + k0 + lq * 8];
#pragma unroll
            for (int ct = 0; ct < CT; ct++)
                b[ct] = *(const short8*)(Wmp + (long long)(ct * 16 + lrow) * KX + k0 + lq * 8);
#pragma unroll
            for (int rt = 0; rt < 4; rt++)
#pragma unroll
                for (int ct = 0; ct < CT; ct++)
                    acch[rt][ct] = __builtin_amdgcn_mfma_f32_16x16x32_bf16(a[rt], b[ct], acch[rt][ct], 0, 0, 0);
        }
    }
    __syncthreads();  // h A-reads done

    // ---- epilogue: X_next = relu(h*SC+SH) * gate -> buf (stride LDN)
#pragma unroll
    for (int ct = 0; ct < CT; ct++) {
        int n = n0w + ct * 16 + lrow;
        float sc = sSC[n], sh = sSH[n];
#pragma unroll
        for (int rt = 0; rt < 4; rt++) {
            float gv[4] = {b2f((unsigned short)(gatep[rt][ct][0] & 0xffff)),
                           b2f((unsigned short)(gatep[rt][ct][0] >> 16)),
                           b2f((unsigned short)(gatep[rt][ct][1] & 0xffff)),
                           b2f((unsigned short)(gatep[rt][ct][1] >> 16))};
#pragma unroll
            for (int r = 0; r < 4; r++) {
                int m = rt * 16 + lq * 4 + r;
                float v = fmaxf(acch[rt][ct][r] * sc + sh, 0.f) * gv[r];
                buf[m * LDN + n] = f2b(v);
            }
        }
    }
    __syncthreads();

    if (!FINAL) {
        unsigned short* Op = Xn + ((long long)d * BATCH + m0) * N;
#pragma unroll
        for (int it = 0; it < TM * (N / 8) / 256; it++) {
            int idx = it * 256 + t;
            int m = idx / (N / 8), j = idx % (N / 8);
            *(uint4*)(Op + (long long)m * N + j * 8) = *(const uint4*)&buf[m * LDN + j * 8];
        }
    } else {
        // out[b] = sigmoid(x3 . finW[d] + finb[d]) where d == dom[b]
        int m = t >> 2, q = t & 3;
        const float* fwp = fw + d * 64;
        float s = 0.f;
#pragma unroll
        for (int k = 0; k < 16; k++) {
            int c = q * 16 + k;
            s += b2f(buf[m * LDN + c]) * fwp[c];
        }
        s += __shfl_down(s, 1);
        s += __shfl_down(s, 2);
        if (q == 0) {
            int b = m0 + m;
            if (dom[b] == d) outp[b] = 1.f / (1.f + __expf(-(s + fb[d])));
        }
    }

    if (NN > 0) {
        // ---- next-layer BN stats: hN_pre = X_next @ WmN
        const int n0wN = w * (NN / 4);
        floatx4 accs[4][CTn];
#pragma unroll
        for (int rt = 0; rt < 4; rt++)
#pragma unroll
            for (int ct = 0; ct < CTn; ct++) accs[rt][ct] = (floatx4)(0.f);
        const unsigned short* Wnp = WmN + ((long long)d * NN + n0wN) * N;
#pragma unroll
        for (int k0 = 0; k0 < N; k0 += 32) {
            short8 a[4], b[CTn];
#pragma unroll
            for (int rt = 0; rt < 4; rt++)
                a[rt] = *(const short8*)&buf[(rt * 16 + lrow) * LDN + k0 + lq * 8];
#pragma unroll
            for (int ct = 0; ct < CTn; ct++)
                b[ct] = *(const short8*)(Wnp + (long long)(ct * 16 + lrow) * N + k0 + lq * 8);
#pragma unroll
            for (int rt = 0; rt < 4; rt++)
#pragma unroll
                for (int ct = 0; ct < CTn; ct++)
                    accs[rt][ct] = __builtin_amdgcn_mfma_f32_16x16x32_bf16(a[rt], b[ct], accs[rt][ct], 0, 0, 0);
        }
#pragma unroll
        for (int ct = 0; ct < CTn; ct++) {
            float s = 0.f, ss = 0.f;
#pragma unroll
            for (int rt = 0; rt < 4; rt++)
#pragma unroll
                for (int r = 0; r < 4; r++) { float v = accs[rt][ct][r]; s += v; ss += v * v; }
            s += __shfl_down(s, 32); ss += __shfl_down(ss, 32);
            s += __shfl_down(s, 16); ss += __shfl_down(ss, 16);
            if (lane < 16) {
                atomicAdd(&sSum[n0wN + ct * 16 + lane], s);
                atomicAdd(&sSsq[n0wN + ct * 16 + lane], ss);
            }
        }
        __syncthreads();
        if (t < NN) {
            atomicAdd(&gsumN[d * NN + t], sSum[t]);
            atomicAdd(&gssqN[d * NN + t], sSsq[t]);
        }
    }
}

// ---------------------------------------------------------------------------
extern "C" void kernel_launch(void* const* d_in, const int* in_sizes, int n_in,
                              void* d_out, int out_size, void* d_ws, size_t ws_size,
                              hipStream_t stream) {
    const int B = BATCH, D = NDOM;

    const int* id_idx = (const int*)d_in[0];
    const int* agn_idx = (const int*)d_in[1];
    const int* dom = (const int*)d_in[2];
    const float* id_t = (const float*)d_in[3];
    const float* agn_t = (const float*)d_in[4];
    const float *mlpW[3], *bng[3], *bnb[3], *gW1[3], *gb1[3], *gW2[3], *gb2[3];
    for (int i = 0; i < 3; i++) {
        int b0 = 5 + i * 8;
        mlpW[i] = (const float*)d_in[b0 + 0];
        bng[i] = (const float*)d_in[b0 + 2];
        bnb[i] = (const float*)d_in[b0 + 3];
        gW1[i] = (const float*)d_in[b0 + 4];
        gb1[i] = (const float*)d_in[b0 + 5];
        gW2[i] = (const float*)d_in[b0 + 6];
        gb2[i] = (const float*)d_in[b0 + 7];
    }
    const float* finW = (const float*)d_in[29];
    const float* finb = (const float*)d_in[30];

    char* wsc = (char*)d_ws;
    size_t off = 0;
    auto alloc = [&](size_t bytes) -> char* {
        char* p = wsc + off;
        off = (off + bytes + 255) & ~(size_t)255;
        return p;
    };

    struct { const float* src; int K, N; } mats[9] = {
        {mlpW[0], 256, 256}, {gW1[0], 256, 256}, {gW2[0], 256, 256},
        {mlpW[1], 256, 128}, {gW1[1], 256, 128}, {gW2[1], 128, 128},
        {mlpW[2], 128, 64},  {gW1[2], 256, 64},  {gW2[2], 64, 64}};
    unsigned pfx[10];
    pfx[0] = 0;
    for (int j = 0; j < 9; j++) pfx[j + 1] = pfx[j] + 4u * mats[j].K * mats[j].N;

    unsigned short* wt = (unsigned short*)alloc((size_t)pfx[9] * 2);
    unsigned short* gin = (unsigned short*)alloc((size_t)B * 256 * 2);
    float* stats = (float*)alloc((size_t)3 * 2 * D * 256 * 4);  // per layer: gsum, gssq
    unsigned short* X1 = (unsigned short*)alloc((size_t)D * B * 256 * 2);
    unsigned short* X2 = (unsigned short*)alloc((size_t)D * B * 128 * 2);

    PrepArgs pa;
    for (int j = 0; j < 9; j++) {
        pa.m[j].src = mats[j].src;
        pa.m[j].K = (unsigned)mats[j].K;
        pa.m[j].N = (unsigned)mats[j].N;
        pa.m[j].pfx = pfx[j];
        pa.m[j].total = 4u * mats[j].K * mats[j].N;
    }
    pa.stats = stats;
    pa.statsN = 3 * 2 * D * 256;
    pa.grand = pfx[9];

    const float invB = 1.f / (float)B;
    dim3 gs(B / TM, D);

    float* gsum0 = stats + 0 * 2 * D * 256; float* gssq0 = gsum0 + D * 256;
    float* gsum1 = stats + 1 * 2 * D * 256; float* gssq1 = gsum1 + D * 256;
    float* gsum2 = stats + 2 * 2 * D * 256; float* gssq2 = gsum2 + D * 256;

    prep_k<<<dim3((pfx[9] + 255) / 256), 256, 0, stream>>>(pa, wt);

    // embed + layer-0 stats fused
    embed_stats_k<<<dim3(B / TM), 256, 0, stream>>>(id_idx, agn_idx, id_t, agn_t,
                                                    wt + pfx[0], gin, gsum0, gssq0);

    // layer 0: N=256, KX=256 (gin), next NN=128
    fused_k<256, 256, 128, true, false><<<gs, 256, 0, stream>>>(
        gin, gin, wt + pfx[1], wt + pfx[2], wt + pfx[0], wt + pfx[3],
        gb1[0], gb2[0], gsum0, gssq0, bng[0], bnb[0], gsum1, gssq1,
        X1, nullptr, nullptr, nullptr, nullptr, invB);

    // layer 1: N=128, KX=256 (X1), next NN=64
    fused_k<128, 256, 64, false, false><<<gs, 256, 0, stream>>>(
        gin, X1, wt + pfx[4], wt + pfx[5], wt + pfx[3], wt + pfx[6],
        gb1[1], gb2[1], gsum1, gssq1, bng[1], bnb[1], gsum2, gssq2,
        X2, nullptr, nullptr, nullptr, nullptr, invB);

    // layer 2: N=64, KX=128 (X2), final dot + sigmoid + domain select
    fused_k<64, 128, 0, false, true><<<gs, 256, 0, stream>>>(
        gin, X2, wt + pfx[7], wt + pfx[8], wt + pfx[6], nullptr,
        gb1[2], gb2[2], gsum2, gssq2, bng[2], bnb[2], nullptr, nullptr,
        nullptr, dom, finW, finb, (float*)d_out, invB);
}